// Round 15
// baseline (11213.396 us; speedup 1.0000x reference)
//
#include <hip/hip_runtime.h>
#include <hip/hip_bf16.h>

#define DIMS 1024
#define SEQ 512
#define BATCH 128
#define VOCAB 32000
#define GRID 256

typedef __attribute__((ext_vector_type(8))) short short8;
typedef __attribute__((ext_vector_type(4))) float f32x4;

__device__ __forceinline__ ushort f2bf(float x) {
    union { float f; unsigned u; } v; v.f = x;
    unsigned u = v.u;
    return (ushort)((u + 0x7FFFu + ((u >> 16) & 1u)) >> 16);
}

__global__ void conv_emb_kernel(const float* __restrict__ in, ushort* __restrict__ out, int n) {
    int idx = blockIdx.x * blockDim.x + threadIdx.x;
    int stride = gridDim.x * blockDim.x;
    for (int i = idx * 4; i < n; i += stride * 4) {
        float4 v = *(const float4*)(in + i);
        ushort4 o;
        o.x = f2bf(v.x); o.y = f2bf(v.y); o.z = f2bf(v.z); o.w = f2bf(v.w);
        *(ushort4*)(out + i) = o;
    }
}

// Persistent LSTM, fence-free flag sync, homogeneous K-split waves.
// R14 + ONE change: the x-leg emb gather for step t+1 is issued (asm-pinned,
// 16x global_load_dwordx4) at the START of step t into a ping-pong register
// buffer; the end-of-step publish-ack vmcnt(0) guarantees residency before
// step t+1 consumes it. x-MFMAs read pure registers (the R14 profile left
// ~8k cyc/step unaccounted = exposed L3 gather latency, same disease the
// h-leg had before R14).
// Grid = 256 blocks x 512 threads; 8 waves = 4 row-quarters x 2 K-halves.
__launch_bounds__(512, 2)
__global__ void lstm_kernel(const int* __restrict__ feats,
                            const ushort* __restrict__ emb,
                            const float* __restrict__ Wf, const float* __restrict__ Uf, const float* __restrict__ bfp,
                            const float* __restrict__ Wi, const float* __restrict__ Ui, const float* __restrict__ bip,
                            const float* __restrict__ Wo, const float* __restrict__ Uo, const float* __restrict__ bop,
                            const float* __restrict__ Wc, const float* __restrict__ Uc, const float* __restrict__ bcp,
                            ushort* __restrict__ hbuf, float* __restrict__ out, int* __restrict__ flags) {
    __shared__ ushort Bl[32 * 2048];        // 131072 B: B-slice, XOR-swizzled
    __shared__ float pre0[64 * 36];         // K-half 0 partial (x+h), pitch 36
    __shared__ float pre1[64 * 36];         // K-half 1 partial (x+h)

    const int tid = threadIdx.x;
    const int bid = blockIdx.x;
    const int rg = bid >> 7;      // row group: rows rg*64 .. rg*64+63
    const int cb = bid & 127;     // d-chunk: d = cb*8 .. cb*8+7

    // ---- one-time: load B slice (f32 -> bf16) into LDS ----
    for (int idx = tid; idx < 32 * 2048; idx += 512) {
        int cl = idx & 31;
        int k  = idx >> 5;
        int g  = cl >> 3, dd0 = cl & 7;
        int dw = cb * 8 + dd0;
        const float* Wg = (g == 0) ? Wf : (g == 1) ? Wi : (g == 2) ? Wo : Wc;
        const float* Ug = (g == 0) ? Uf : (g == 1) ? Ui : (g == 2) ? Uo : Uc;
        float v = (k < 1024) ? Wg[k * 1024 + dw] : Ug[(k - 1024) * 1024 + dw];
        int boff = ((cl << 12) | (k << 1)) ^ ((cl & 7) << 4);
        *(ushort*)((char*)Bl + boff) = f2bf(v);
    }

    const int lane = tid & 63;
    const int w  = tid >> 6;                 // wave 0..7
    const int wr = w & 3;                    // row quarter: rows wr*16..wr*16+15
    const int kh = w >> 2;                   // K-half: 0 or 1
    const int lx = lane & 15;
    const int qq = lane >> 4;
    const int kg = qq * 8;
    const int lr = wr * 16 + lx;             // local row within row-group
    const int brow = rg * 64 + lr;           // global batch row

    const int bofs0 = (lx << 12) ^ ((lx & 7) << 4);
    const int bofs1 = ((16 + lx) << 12) ^ ((lx & 7) << 4);

    const int kb    = kh * 512;              // K-half base
    const int fbase = kh * 64;               // producer flag/chunk base for h half
    float* myPre = kh ? pre1 : pre0;
    const int r0 = wr * 16 + qq * 4;         // C/D row base (col = lx, row = r0+reg)

    // gate-phase mapping: 1 state per thread: row = tid>>3, dd = tid&7
    const int grow_ = tid >> 3;
    const int gdd   = tid & 7;
    const int gd    = cb * 8 + gdd;
    const float bF = bfp[gd], bI = bip[gd], bO = bop[gd], bC = bcp[gd];

    float cst = 0.f;
    int* myflags = flags + rg * 128;

    __syncthreads();   // Bl ready

    short8 xA[16], xB[16];                   // ping-pong x fragment buffers
    int fidxn;                               // feat index for the NEXT issue

    // ---- prologue: issue x(0) into xA, prefetch feats[1] ----
    {
        int f0 = feats[brow * SEQ];
        const ushort* xr = emb + (size_t)f0 * DIMS + kb;
        #pragma unroll
        for (int ks = 0; ks < 16; ks++) {
            const ushort* xp = xr + ks * 32 + kg;
            asm volatile("global_load_dwordx4 %0, %1, off" : "=v"(xA[ks]) : "v"(xp) : "memory");
        }
        fidxn = feats[brow * SEQ + 1];
        asm volatile("s_waitcnt vmcnt(0)" ::: "memory");
    }

    auto body = [&](int t, short8 (&xc)[16], short8 (&xn)[16]) {
        f32x4 a00 = {0,0,0,0}, a01 = {0,0,0,0};
        f32x4 a10 = {0,0,0,0}, a11 = {0,0,0,0};

        // ---- issue x(t+1) prefetch (a full step of flight time) ----
        if (t + 1 < SEQ) {
            const ushort* xr = emb + (size_t)fidxn * DIMS + kb;
            #pragma unroll
            for (int ks = 0; ks < 16; ks++) {
                const ushort* xp = xr + ks * 32 + kg;
                asm volatile("global_load_dwordx4 %0, %1, off" : "=v"(xn[ks]) : "v"(xp) : "memory");
            }
            if (t + 2 < SEQ) fidxn = feats[brow * SEQ + t + 2];
        }

        // ---- x @ W iters 0..7 from registers (covers flag propagation) ----
        #pragma unroll
        for (int ks = 0; ks < 8; ks += 2) {
            {
                int k = kb + ks * 32 + kg;
                short8 b0 = *(const short8*)((const char*)Bl + (bofs0 ^ (k << 1)));
                short8 b1 = *(const short8*)((const char*)Bl + (bofs1 ^ (k << 1)));
                a00 = __builtin_amdgcn_mfma_f32_16x16x32_bf16(xc[ks], b0, a00, 0, 0, 0);
                a10 = __builtin_amdgcn_mfma_f32_16x16x32_bf16(xc[ks], b1, a10, 0, 0, 0);
            }
            {
                int k = kb + (ks + 1) * 32 + kg;
                short8 b0 = *(const short8*)((const char*)Bl + (bofs0 ^ (k << 1)));
                short8 b1 = *(const short8*)((const char*)Bl + (bofs1 ^ (k << 1)));
                a01 = __builtin_amdgcn_mfma_f32_16x16x32_bf16(xc[ks + 1], b0, a01, 0, 0, 0);
                a11 = __builtin_amdgcn_mfma_f32_16x16x32_bf16(xc[ks + 1], b1, a11, 0, 0, 0);
            }
        }

        // ---- poll + pinned issue of all 16 h-loads (coherent, batched) ----
        short8 hv[16];
        if (t > 0) {
            long guard = 0;
            for (;;) {
                int f0 = __hip_atomic_load(myflags + fbase + lane, __ATOMIC_RELAXED, __HIP_MEMORY_SCOPE_AGENT);
                if (__all(f0 >= t)) break;
                __builtin_amdgcn_s_sleep(1);
                if (++guard > 100000000L) break;  // deadlock safety valve
            }
            const ushort* hbase = hbuf + (size_t)((t & 1) * 2 + rg) * (128 * 512);
            #pragma unroll
            for (int ks = 0; ks < 16; ks++) {
                const ushort* hp = hbase + ((fbase + ks * 4 + qq) << 9) + lr * 8;
                asm volatile("global_load_dwordx4 %0, %1, off sc0 sc1"
                             : "=v"(hv[ks]) : "v"(hp) : "memory");
            }
        }

        // ---- x @ W iters 8..15 (hides h-load flight) ----
        #pragma unroll
        for (int ks = 8; ks < 16; ks += 2) {
            {
                int k = kb + ks * 32 + kg;
                short8 b0 = *(const short8*)((const char*)Bl + (bofs0 ^ (k << 1)));
                short8 b1 = *(const short8*)((const char*)Bl + (bofs1 ^ (k << 1)));
                a00 = __builtin_amdgcn_mfma_f32_16x16x32_bf16(xc[ks], b0, a00, 0, 0, 0);
                a10 = __builtin_amdgcn_mfma_f32_16x16x32_bf16(xc[ks], b1, a10, 0, 0, 0);
            }
            {
                int k = kb + (ks + 1) * 32 + kg;
                short8 b0 = *(const short8*)((const char*)Bl + (bofs0 ^ (k << 1)));
                short8 b1 = *(const short8*)((const char*)Bl + (bofs1 ^ (k << 1)));
                a01 = __builtin_amdgcn_mfma_f32_16x16x32_bf16(xc[ks + 1], b0, a01, 0, 0, 0);
                a11 = __builtin_amdgcn_mfma_f32_16x16x32_bf16(xc[ks + 1], b1, a11, 0, 0, 0);
            }
        }

        // ---- h @ U MFMA loop: wait once, then registers + LDS only ----
        if (t > 0) {
            asm volatile("s_waitcnt vmcnt(0)" ::: "memory");  // hv (and xn) resident
            __builtin_amdgcn_sched_barrier(0);
            #pragma unroll
            for (int ks = 0; ks < 16; ks += 2) {
                {
                    int k = 1024 + kb + ks * 32 + kg;
                    short8 b0 = *(const short8*)((const char*)Bl + (bofs0 ^ (k << 1)));
                    short8 b1 = *(const short8*)((const char*)Bl + (bofs1 ^ (k << 1)));
                    a00 = __builtin_amdgcn_mfma_f32_16x16x32_bf16(hv[ks], b0, a00, 0, 0, 0);
                    a10 = __builtin_amdgcn_mfma_f32_16x16x32_bf16(hv[ks], b1, a10, 0, 0, 0);
                }
                {
                    int k = 1024 + kb + (ks + 1) * 32 + kg;
                    short8 b0 = *(const short8*)((const char*)Bl + (bofs0 ^ (k << 1)));
                    short8 b1 = *(const short8*)((const char*)Bl + (bofs1 ^ (k << 1)));
                    a01 = __builtin_amdgcn_mfma_f32_16x16x32_bf16(hv[ks + 1], b0, a01, 0, 0, 0);
                    a11 = __builtin_amdgcn_mfma_f32_16x16x32_bf16(hv[ks + 1], b1, a11, 0, 0, 0);
                }
            }
        }

        // ---- write partials (C/D layout: col = lane&15, row = (lane>>4)*4 + reg) ----
        #pragma unroll
        for (int j = 0; j < 4; j++) {
            myPre[(r0 + j) * 36 + lx]      = a00[j] + a01[j];
            myPre[(r0 + j) * 36 + 16 + lx] = a10[j] + a11[j];
        }
        __syncthreads();   // sync A: pre0 + pre1 complete

        // ---- gates: 1 state per thread ----
        {
            int base = grow_ * 36;
            float pf = pre0[base + gdd]      + pre1[base + gdd]      + bF;
            float pi = pre0[base + 8 + gdd]  + pre1[base + 8 + gdd]  + bI;
            float po = pre0[base + 16 + gdd] + pre1[base + 16 + gdd] + bO;
            float pc = pre0[base + 24 + gdd] + pre1[base + 24 + gdd] + bC;
            float f  = 1.f / (1.f + __expf(-pf));
            float ig = 1.f / (1.f + __expf(-pi));
            float o  = 1.f / (1.f + __expf(-po));
            float e2 = __expf(2.f * pc);
            float cc = (e2 - 1.f) / (e2 + 1.f);
            float cn = f * cst + ig * cc;
            cst = cn;
            float e2c = __expf(2.f * cn);
            float th  = (e2c - 1.f) / (e2c + 1.f);
            float h   = o * th;
            if (t < SEQ - 1) {
                // coalesced publish: thread tid -> hnext[cb*512 + tid]
                ushort* hw = hbuf + (size_t)(((t + 1) & 1) * 2 + rg) * (128 * 512) + cb * 512 + tid;
                __hip_atomic_store(hw, f2bf(h), __ATOMIC_RELAXED, __HIP_MEMORY_SCOPE_AGENT);
            } else {
                int gr = rg * 64 + grow_;
                out[gr * 2048 + gd] = h;
                out[gr * 2048 + 1024 + gd] = cn;
            }
        }

        if (t < SEQ - 1) {
            asm volatile("s_waitcnt vmcnt(0)" ::: "memory");  // publish acked; xn resident too
            __syncthreads();                                   // sync B
            if (tid == 0) {
                __hip_atomic_store(myflags + cb, t + 1, __ATOMIC_RELAXED, __HIP_MEMORY_SCOPE_AGENT);
            }
        }
    };

    for (int t = 0; t < SEQ; t += 2) {
        body(t, xA, xB);
        body(t + 1, xB, xA);
    }
}

extern "C" void kernel_launch(void* const* d_in, const int* in_sizes, int n_in,
                              void* d_out, int out_size, void* d_ws, size_t ws_size,
                              hipStream_t stream) {
    const int*   feats = (const int*)d_in[0];
    const float* emb_f = (const float*)d_in[1];
    const float* Wf = (const float*)d_in[2];
    const float* Uf = (const float*)d_in[3];
    const float* bf_ = (const float*)d_in[4];
    const float* Wi = (const float*)d_in[5];
    const float* Ui = (const float*)d_in[6];
    const float* bi_ = (const float*)d_in[7];
    const float* Wo = (const float*)d_in[8];
    const float* Uo = (const float*)d_in[9];
    const float* bo_ = (const float*)d_in[10];
    const float* Wc = (const float*)d_in[11];
    const float* Uc = (const float*)d_in[12];
    const float* bc_ = (const float*)d_in[13];

    char* ws = (char*)d_ws;
    ushort* emb_bf = (ushort*)ws;                          // 65,536,000 B
    ushort* hbuf   = (ushort*)(ws + 65536000);             // 2x2x128x64x8 bf16 = 524,288 B
    int*    flags  = (int*)(ws + 65536000 + 524288);       // 256 flags

    hipMemsetAsync(flags, 0, 1024, stream);
    conv_emb_kernel<<<1024, 256, 0, stream>>>(emb_f, emb_bf, VOCAB * DIMS);
    lstm_kernel<<<GRID, 512, 0, stream>>>(feats, emb_bf,
                                          Wf, Uf, bf_, Wi, Ui, bi_,
                                          Wo, Uo, bo_, Wc, Uc, bc_,
                                          hbuf, (float*)d_out, flags);
}

// Round 16
// 4398.078 us; speedup vs baseline: 2.5496x; 2.5496x over previous
//
#include <hip/hip_runtime.h>
#include <hip/hip_bf16.h>

#define DIMS 1024
#define SEQ 512
#define BATCH 128
#define VOCAB 32000
#define GRID 256

typedef __attribute__((ext_vector_type(8))) short short8;
typedef __attribute__((ext_vector_type(4))) float f32x4;

__device__ __forceinline__ ushort f2bf(float x) {
    union { float f; unsigned u; } v; v.f = x;
    unsigned u = v.u;
    return (ushort)((u + 0x7FFFu + ((u >> 16) & 1u)) >> 16);
}

__global__ void conv_emb_kernel(const float* __restrict__ in, ushort* __restrict__ out, int n) {
    int idx = blockIdx.x * blockDim.x + threadIdx.x;
    int stride = gridDim.x * blockDim.x;
    for (int i = idx * 4; i < n; i += stride * 4) {
        float4 v = *(const float4*)(in + i);
        ushort4 o;
        o.x = f2bf(v.x); o.y = f2bf(v.y); o.z = f2bf(v.z); o.w = f2bf(v.w);
        *(ushort4*)(out + i) = o;
    }
}

// Persistent LSTM, fence-free flag sync, homogeneous K-split waves.
// R14 + batched x-loads via counted vmcnt (R15's prefetch concept redone
// WITHOUT the lambda/ping-pong that spilled to scratch — R15's FETCH_SIZE
// went 10x = scratch traffic, VGPR 128 = arrays demoted):
//   issue 16 x-loads -> poll (x flies during spin) -> issue 16 h-loads
//   -> vmcnt(16) waits ONLY the x-loads -> x-MFMA (h flies)
//   -> vmcnt(0) -> h-MFMA. All arrays static-indexed, single live window.
// Grid = 256 blocks x 512 threads; 8 waves = 4 row-quarters x 2 K-halves.
__launch_bounds__(512, 2)
__global__ void lstm_kernel(const int* __restrict__ feats,
                            const ushort* __restrict__ emb,
                            const float* __restrict__ Wf, const float* __restrict__ Uf, const float* __restrict__ bfp,
                            const float* __restrict__ Wi, const float* __restrict__ Ui, const float* __restrict__ bip,
                            const float* __restrict__ Wo, const float* __restrict__ Uo, const float* __restrict__ bop,
                            const float* __restrict__ Wc, const float* __restrict__ Uc, const float* __restrict__ bcp,
                            ushort* __restrict__ hbuf, float* __restrict__ out, int* __restrict__ flags) {
    __shared__ ushort Bl[32 * 2048];        // 131072 B: B-slice, XOR-swizzled
    __shared__ float pre0[64 * 36];         // K-half 0 partial (x+h), pitch 36
    __shared__ float pre1[64 * 36];         // K-half 1 partial (x+h)

    const int tid = threadIdx.x;
    const int bid = blockIdx.x;
    const int rg = bid >> 7;      // row group: rows rg*64 .. rg*64+63
    const int cb = bid & 127;     // d-chunk: d = cb*8 .. cb*8+7

    // ---- one-time: load B slice (f32 -> bf16) into LDS ----
    for (int idx = tid; idx < 32 * 2048; idx += 512) {
        int cl = idx & 31;
        int k  = idx >> 5;
        int g  = cl >> 3, dd0 = cl & 7;
        int dw = cb * 8 + dd0;
        const float* Wg = (g == 0) ? Wf : (g == 1) ? Wi : (g == 2) ? Wo : Wc;
        const float* Ug = (g == 0) ? Uf : (g == 1) ? Ui : (g == 2) ? Uo : Uc;
        float v = (k < 1024) ? Wg[k * 1024 + dw] : Ug[(k - 1024) * 1024 + dw];
        int boff = ((cl << 12) | (k << 1)) ^ ((cl & 7) << 4);
        *(ushort*)((char*)Bl + boff) = f2bf(v);
    }

    const int lane = tid & 63;
    const int w  = tid >> 6;                 // wave 0..7
    const int wr = w & 3;                    // row quarter: rows wr*16..wr*16+15
    const int kh = w >> 2;                   // K-half: 0 or 1
    const int lx = lane & 15;
    const int qq = lane >> 4;
    const int kg = qq * 8;
    const int lr = wr * 16 + lx;             // local row within row-group
    const int brow = rg * 64 + lr;           // global batch row

    const int bofs0 = (lx << 12) ^ ((lx & 7) << 4);
    const int bofs1 = ((16 + lx) << 12) ^ ((lx & 7) << 4);

    const int kb    = kh * 512;              // K-half base
    const int fbase = kh * 64;               // producer flag/chunk base for h half
    float* myPre = kh ? pre1 : pre0;
    const int r0 = wr * 16 + qq * 4;         // C/D row base (col = lx, row = r0+reg)

    // gate-phase mapping: 1 state per thread: row = tid>>3, dd = tid&7
    const int grow_ = tid >> 3;
    const int gdd   = tid & 7;
    const int gd    = cb * 8 + gdd;
    const float bF = bfp[gd], bI = bip[gd], bO = bop[gd], bC = bcp[gd];

    float cst = 0.f;
    int* myflags = flags + rg * 128;
    int fidx = feats[brow * SEQ];

    __syncthreads();   // Bl ready

    for (int t = 0; t < SEQ; t++) {
        f32x4 a00 = {0,0,0,0}, a01 = {0,0,0,0};   // n-tile 0, even/odd k-step
        f32x4 a10 = {0,0,0,0}, a11 = {0,0,0,0};   // n-tile 1, even/odd k-step

        // ---- issue all 16 x-loads (fly during the poll) ----
        short8 xv[16];
        {
            const ushort* xrow = emb + (size_t)fidx * DIMS + kb;
            #pragma unroll
            for (int ks = 0; ks < 16; ks++) {
                const ushort* xp = xrow + ks * 32 + kg;
                asm volatile("global_load_dwordx4 %0, %1, off"
                             : "=v"(xv[ks]) : "v"(xp) : "memory");
            }
            fidx = (t + 1 < SEQ) ? feats[brow * SEQ + t + 1] : 0;
        }

        // ---- poll + issue all 16 h-loads (coherent, batched) ----
        short8 hv[16];
        if (t > 0) {
            long guard = 0;
            for (;;) {
                int f0 = __hip_atomic_load(myflags + fbase + lane, __ATOMIC_RELAXED, __HIP_MEMORY_SCOPE_AGENT);
                if (__all(f0 >= t)) break;
                __builtin_amdgcn_s_sleep(1);
                if (++guard > 100000000L) break;  // deadlock safety valve
            }
            const ushort* hbase = hbuf + (size_t)((t & 1) * 2 + rg) * (128 * 512);
            #pragma unroll
            for (int ks = 0; ks < 16; ks++) {
                const ushort* hp = hbase + ((fbase + ks * 4 + qq) << 9) + lr * 8;
                asm volatile("global_load_dwordx4 %0, %1, off sc0 sc1"
                             : "=v"(hv[ks]) : "v"(hp) : "memory");
            }
            // wait the 16 OLDEST outstanding ops = the x-loads; h stays in flight
            asm volatile("s_waitcnt vmcnt(16)" ::: "memory");
        } else {
            asm volatile("s_waitcnt vmcnt(0)" ::: "memory");
        }
        __builtin_amdgcn_sched_barrier(0);

        // ---- x @ W: 16 k-steps from registers (h-loads in flight) ----
        #pragma unroll
        for (int ks = 0; ks < 16; ks += 2) {
            {
                int k = kb + ks * 32 + kg;
                short8 b0 = *(const short8*)((const char*)Bl + (bofs0 ^ (k << 1)));
                short8 b1 = *(const short8*)((const char*)Bl + (bofs1 ^ (k << 1)));
                a00 = __builtin_amdgcn_mfma_f32_16x16x32_bf16(xv[ks], b0, a00, 0, 0, 0);
                a10 = __builtin_amdgcn_mfma_f32_16x16x32_bf16(xv[ks], b1, a10, 0, 0, 0);
            }
            {
                int k = kb + (ks + 1) * 32 + kg;
                short8 b0 = *(const short8*)((const char*)Bl + (bofs0 ^ (k << 1)));
                short8 b1 = *(const short8*)((const char*)Bl + (bofs1 ^ (k << 1)));
                a01 = __builtin_amdgcn_mfma_f32_16x16x32_bf16(xv[ks + 1], b0, a01, 0, 0, 0);
                a11 = __builtin_amdgcn_mfma_f32_16x16x32_bf16(xv[ks + 1], b1, a11, 0, 0, 0);
            }
        }

        // ---- h @ U: wait h, then registers + LDS only ----
        if (t > 0) {
            asm volatile("s_waitcnt vmcnt(0)" ::: "memory");
            __builtin_amdgcn_sched_barrier(0);   // rule #18
            #pragma unroll
            for (int ks = 0; ks < 16; ks += 2) {
                {
                    int k = 1024 + kb + ks * 32 + kg;
                    short8 b0 = *(const short8*)((const char*)Bl + (bofs0 ^ (k << 1)));
                    short8 b1 = *(const short8*)((const char*)Bl + (bofs1 ^ (k << 1)));
                    a00 = __builtin_amdgcn_mfma_f32_16x16x32_bf16(hv[ks], b0, a00, 0, 0, 0);
                    a10 = __builtin_amdgcn_mfma_f32_16x16x32_bf16(hv[ks], b1, a10, 0, 0, 0);
                }
                {
                    int k = 1024 + kb + (ks + 1) * 32 + kg;
                    short8 b0 = *(const short8*)((const char*)Bl + (bofs0 ^ (k << 1)));
                    short8 b1 = *(const short8*)((const char*)Bl + (bofs1 ^ (k << 1)));
                    a01 = __builtin_amdgcn_mfma_f32_16x16x32_bf16(hv[ks + 1], b0, a01, 0, 0, 0);
                    a11 = __builtin_amdgcn_mfma_f32_16x16x32_bf16(hv[ks + 1], b1, a11, 0, 0, 0);
                }
            }
        }

        // ---- write partials (C/D layout: col = lane&15, row = (lane>>4)*4 + reg) ----
        #pragma unroll
        for (int j = 0; j < 4; j++) {
            myPre[(r0 + j) * 36 + lx]      = a00[j] + a01[j];
            myPre[(r0 + j) * 36 + 16 + lx] = a10[j] + a11[j];
        }
        __syncthreads();   // sync A: pre0 + pre1 complete

        // ---- gates: 1 state per thread ----
        {
            int base = grow_ * 36;
            float pf = pre0[base + gdd]      + pre1[base + gdd]      + bF;
            float pi = pre0[base + 8 + gdd]  + pre1[base + 8 + gdd]  + bI;
            float po = pre0[base + 16 + gdd] + pre1[base + 16 + gdd] + bO;
            float pc = pre0[base + 24 + gdd] + pre1[base + 24 + gdd] + bC;
            float f  = 1.f / (1.f + __expf(-pf));
            float ig = 1.f / (1.f + __expf(-pi));
            float o  = 1.f / (1.f + __expf(-po));
            float e2 = __expf(2.f * pc);
            float cc = (e2 - 1.f) / (e2 + 1.f);
            float cn = f * cst + ig * cc;
            cst = cn;
            float e2c = __expf(2.f * cn);
            float th  = (e2c - 1.f) / (e2c + 1.f);
            float h   = o * th;
            if (t < SEQ - 1) {
                // coalesced publish: thread tid -> hnext[cb*512 + tid]
                ushort* hw = hbuf + (size_t)(((t + 1) & 1) * 2 + rg) * (128 * 512) + cb * 512 + tid;
                __hip_atomic_store(hw, f2bf(h), __ATOMIC_RELAXED, __HIP_MEMORY_SCOPE_AGENT);
            } else {
                int gr = rg * 64 + grow_;
                out[gr * 2048 + gd] = h;
                out[gr * 2048 + 1024 + gd] = cn;
            }
        }

        if (t < SEQ - 1) {
            asm volatile("s_waitcnt vmcnt(0)" ::: "memory");  // h stores acked at coherence point
            __syncthreads();                                   // sync B: publishes done; pre[] reusable
            if (tid == 0) {
                __hip_atomic_store(myflags + cb, t + 1, __ATOMIC_RELAXED, __HIP_MEMORY_SCOPE_AGENT);
            }
        }
    }
}

extern "C" void kernel_launch(void* const* d_in, const int* in_sizes, int n_in,
                              void* d_out, int out_size, void* d_ws, size_t ws_size,
                              hipStream_t stream) {
    const int*   feats = (const int*)d_in[0];
    const float* emb_f = (const float*)d_in[1];
    const float* Wf = (const float*)d_in[2];
    const float* Uf = (const float*)d_in[3];
    const float* bf_ = (const float*)d_in[4];
    const float* Wi = (const float*)d_in[5];
    const float* Ui = (const float*)d_in[6];
    const float* bi_ = (const float*)d_in[7];
    const float* Wo = (const float*)d_in[8];
    const float* Uo = (const float*)d_in[9];
    const float* bo_ = (const float*)d_in[10];
    const float* Wc = (const float*)d_in[11];
    const float* Uc = (const float*)d_in[12];
    const float* bc_ = (const float*)d_in[13];

    char* ws = (char*)d_ws;
    ushort* emb_bf = (ushort*)ws;                          // 65,536,000 B
    ushort* hbuf   = (ushort*)(ws + 65536000);             // 2x2x128x64x8 bf16 = 524,288 B
    int*    flags  = (int*)(ws + 65536000 + 524288);       // 256 flags

    hipMemsetAsync(flags, 0, 1024, stream);
    conv_emb_kernel<<<1024, 256, 0, stream>>>(emb_f, emb_bf, VOCAB * DIMS);
    lstm_kernel<<<GRID, 512, 0, stream>>>(feats, emb_bf,
                                          Wf, Uf, bf_, Wi, Ui, bi_,
                                          Wo, Uo, bo_, Wc, Uc, bc_,
                                          hbuf, (float*)d_out, flags);
}

// Round 17
// 4037.708 us; speedup vs baseline: 2.7772x; 1.0893x over previous
//
#include <hip/hip_runtime.h>
#include <hip/hip_bf16.h>

#define DIMS 1024
#define SEQ 512
#define BATCH 128
#define VOCAB 32000
#define GRID 256

typedef __attribute__((ext_vector_type(8))) short short8;
typedef __attribute__((ext_vector_type(4))) float f32x4;

__device__ __forceinline__ ushort f2bf(float x) {
    union { float f; unsigned u; } v; v.f = x;
    unsigned u = v.u;
    return (ushort)((u + 0x7FFFu + ((u >> 16) & 1u)) >> 16);
}

__global__ void conv_emb_kernel(const float* __restrict__ in, ushort* __restrict__ out, int n) {
    int idx = blockIdx.x * blockDim.x + threadIdx.x;
    int stride = gridDim.x * blockDim.x;
    for (int i = idx * 4; i < n; i += stride * 4) {
        float4 v = *(const float4*)(in + i);
        ushort4 o;
        o.x = f2bf(v.x); o.y = f2bf(v.y); o.z = f2bf(v.z); o.w = f2bf(v.w);
        *(ushort4*)(out + i) = o;
    }
}

// Persistent LSTM, fence-free flag sync, homogeneous K-split waves.
// R14 + tail x-prefetch: at the END of step t (right after the publish store
// is issued) all 16 x-loads for t+1 are issued into a single loop-carried
// register buffer xv[16]; they fly concurrently with the publish-ack +
// barrier + flag window and are drained by syncB's vmcnt(0). The step head
// then runs x-MFMA iters 0-7 from pure registers — removing R14's only
// remaining head exposure (first x-load latency) — and reaches the poll
// earlier. Everything else identical to R14 (poll -> h-issue -> x iters
// 8-15 -> vmcnt(0) -> h-MFMA). No lambdas / no address-taken arrays (R15
// spilled via by-reference ping-pong: FETCH 10x; R16 lost by polling before
// any x work). Grid 256 x 512; 8 waves = 4 row-quarters x 2 K-halves.
__launch_bounds__(512, 2)
__global__ void lstm_kernel(const int* __restrict__ feats,
                            const ushort* __restrict__ emb,
                            const float* __restrict__ Wf, const float* __restrict__ Uf, const float* __restrict__ bfp,
                            const float* __restrict__ Wi, const float* __restrict__ Ui, const float* __restrict__ bip,
                            const float* __restrict__ Wo, const float* __restrict__ Uo, const float* __restrict__ bop,
                            const float* __restrict__ Wc, const float* __restrict__ Uc, const float* __restrict__ bcp,
                            ushort* __restrict__ hbuf, float* __restrict__ out, int* __restrict__ flags) {
    __shared__ ushort Bl[32 * 2048];        // 131072 B: B-slice, XOR-swizzled
    __shared__ float pre0[64 * 36];         // K-half 0 partial (x+h), pitch 36
    __shared__ float pre1[64 * 36];         // K-half 1 partial (x+h)

    const int tid = threadIdx.x;
    const int bid = blockIdx.x;
    const int rg = bid >> 7;      // row group: rows rg*64 .. rg*64+63
    const int cb = bid & 127;     // d-chunk: d = cb*8 .. cb*8+7

    // ---- one-time: load B slice (f32 -> bf16) into LDS ----
    for (int idx = tid; idx < 32 * 2048; idx += 512) {
        int cl = idx & 31;
        int k  = idx >> 5;
        int g  = cl >> 3, dd0 = cl & 7;
        int dw = cb * 8 + dd0;
        const float* Wg = (g == 0) ? Wf : (g == 1) ? Wi : (g == 2) ? Wo : Wc;
        const float* Ug = (g == 0) ? Uf : (g == 1) ? Ui : (g == 2) ? Uo : Uc;
        float v = (k < 1024) ? Wg[k * 1024 + dw] : Ug[(k - 1024) * 1024 + dw];
        int boff = ((cl << 12) | (k << 1)) ^ ((cl & 7) << 4);
        *(ushort*)((char*)Bl + boff) = f2bf(v);
    }

    const int lane = tid & 63;
    const int w  = tid >> 6;                 // wave 0..7
    const int wr = w & 3;                    // row quarter: rows wr*16..wr*16+15
    const int kh = w >> 2;                   // K-half: 0 or 1
    const int lx = lane & 15;
    const int qq = lane >> 4;
    const int kg = qq * 8;
    const int lr = wr * 16 + lx;             // local row within row-group
    const int brow = rg * 64 + lr;           // global batch row

    const int bofs0 = (lx << 12) ^ ((lx & 7) << 4);
    const int bofs1 = ((16 + lx) << 12) ^ ((lx & 7) << 4);

    const int kb    = kh * 512;              // K-half base
    const int fbase = kh * 64;               // producer flag/chunk base for h half
    float* myPre = kh ? pre1 : pre0;
    const int r0 = wr * 16 + qq * 4;         // C/D row base (col = lx, row = r0+reg)

    // gate-phase mapping: 1 state per thread: row = tid>>3, dd = tid&7
    const int grow_ = tid >> 3;
    const int gdd   = tid & 7;
    const int gd    = cb * 8 + gdd;
    const float bF = bfp[gd], bI = bip[gd], bO = bop[gd], bC = bcp[gd];

    float cst = 0.f;
    int* myflags = flags + rg * 128;

    __syncthreads();   // Bl ready

    // loop-carried x fragment buffer (written at tail, consumed at next head;
    // static indexing only — never address-taken)
    short8 xv[16];
    int fidxn;   // feat index for the NEXT prefetch issue

    // ---- prologue: issue x(0) loads ----
    {
        int f0 = feats[brow * SEQ];
        const ushort* xr = emb + (size_t)f0 * DIMS + kb;
        #pragma unroll
        for (int ks = 0; ks < 16; ks++) {
            const ushort* xp = xr + ks * 32 + kg;
            asm volatile("global_load_dwordx4 %0, %1, off" : "=v"(xv[ks]) : "v"(xp) : "memory");
        }
        fidxn = feats[brow * SEQ + 1];
        asm volatile("s_waitcnt vmcnt(0)" ::: "memory");
    }

    for (int t = 0; t < SEQ; t++) {
        f32x4 a00 = {0,0,0,0}, a01 = {0,0,0,0};   // n-tile 0, even/odd k-step
        f32x4 a10 = {0,0,0,0}, a11 = {0,0,0,0};   // n-tile 1, even/odd k-step

        // ---- x @ W iters 0..7 from registers (covers flag propagation) ----
        #pragma unroll
        for (int ks = 0; ks < 8; ks += 2) {
            {
                int k = kb + ks * 32 + kg;
                short8 b0 = *(const short8*)((const char*)Bl + (bofs0 ^ (k << 1)));
                short8 b1 = *(const short8*)((const char*)Bl + (bofs1 ^ (k << 1)));
                a00 = __builtin_amdgcn_mfma_f32_16x16x32_bf16(xv[ks], b0, a00, 0, 0, 0);
                a10 = __builtin_amdgcn_mfma_f32_16x16x32_bf16(xv[ks], b1, a10, 0, 0, 0);
            }
            {
                int k = kb + (ks + 1) * 32 + kg;
                short8 b0 = *(const short8*)((const char*)Bl + (bofs0 ^ (k << 1)));
                short8 b1 = *(const short8*)((const char*)Bl + (bofs1 ^ (k << 1)));
                a01 = __builtin_amdgcn_mfma_f32_16x16x32_bf16(xv[ks + 1], b0, a01, 0, 0, 0);
                a11 = __builtin_amdgcn_mfma_f32_16x16x32_bf16(xv[ks + 1], b1, a11, 0, 0, 0);
            }
        }

        // ---- poll + pinned issue of all 16 h-loads (coherent, batched) ----
        short8 hv[16];
        if (t > 0) {
            long guard = 0;
            for (;;) {
                int f0 = __hip_atomic_load(myflags + fbase + lane, __ATOMIC_RELAXED, __HIP_MEMORY_SCOPE_AGENT);
                if (__all(f0 >= t)) break;
                __builtin_amdgcn_s_sleep(1);
                if (++guard > 100000000L) break;  // deadlock safety valve
            }
            const ushort* hbase = hbuf + (size_t)((t & 1) * 2 + rg) * (128 * 512);
            #pragma unroll
            for (int ks = 0; ks < 16; ks++) {
                const ushort* hp = hbase + ((fbase + ks * 4 + qq) << 9) + lr * 8;
                asm volatile("global_load_dwordx4 %0, %1, off sc0 sc1"
                             : "=v"(hv[ks]) : "v"(hp) : "memory");
            }
        }

        // ---- x @ W iters 8..15 from registers (hides h-load flight) ----
        #pragma unroll
        for (int ks = 8; ks < 16; ks += 2) {
            {
                int k = kb + ks * 32 + kg;
                short8 b0 = *(const short8*)((const char*)Bl + (bofs0 ^ (k << 1)));
                short8 b1 = *(const short8*)((const char*)Bl + (bofs1 ^ (k << 1)));
                a00 = __builtin_amdgcn_mfma_f32_16x16x32_bf16(xv[ks], b0, a00, 0, 0, 0);
                a10 = __builtin_amdgcn_mfma_f32_16x16x32_bf16(xv[ks], b1, a10, 0, 0, 0);
            }
            {
                int k = kb + (ks + 1) * 32 + kg;
                short8 b0 = *(const short8*)((const char*)Bl + (bofs0 ^ (k << 1)));
                short8 b1 = *(const short8*)((const char*)Bl + (bofs1 ^ (k << 1)));
                a01 = __builtin_amdgcn_mfma_f32_16x16x32_bf16(xv[ks + 1], b0, a01, 0, 0, 0);
                a11 = __builtin_amdgcn_mfma_f32_16x16x32_bf16(xv[ks + 1], b1, a11, 0, 0, 0);
            }
        }

        // ---- h @ U MFMA loop: wait once, then registers + LDS only ----
        if (t > 0) {
            asm volatile("s_waitcnt vmcnt(0)" ::: "memory");
            __builtin_amdgcn_sched_barrier(0);   // rule #18
            #pragma unroll
            for (int ks = 0; ks < 16; ks += 2) {
                {
                    int k = 1024 + kb + ks * 32 + kg;
                    short8 b0 = *(const short8*)((const char*)Bl + (bofs0 ^ (k << 1)));
                    short8 b1 = *(const short8*)((const char*)Bl + (bofs1 ^ (k << 1)));
                    a00 = __builtin_amdgcn_mfma_f32_16x16x32_bf16(hv[ks], b0, a00, 0, 0, 0);
                    a10 = __builtin_amdgcn_mfma_f32_16x16x32_bf16(hv[ks], b1, a10, 0, 0, 0);
                }
                {
                    int k = 1024 + kb + (ks + 1) * 32 + kg;
                    short8 b0 = *(const short8*)((const char*)Bl + (bofs0 ^ (k << 1)));
                    short8 b1 = *(const short8*)((const char*)Bl + (bofs1 ^ (k << 1)));
                    a01 = __builtin_amdgcn_mfma_f32_16x16x32_bf16(hv[ks + 1], b0, a01, 0, 0, 0);
                    a11 = __builtin_amdgcn_mfma_f32_16x16x32_bf16(hv[ks + 1], b1, a11, 0, 0, 0);
                }
            }
        }

        // ---- write partials (C/D layout: col = lane&15, row = (lane>>4)*4 + reg) ----
        #pragma unroll
        for (int j = 0; j < 4; j++) {
            myPre[(r0 + j) * 36 + lx]      = a00[j] + a01[j];
            myPre[(r0 + j) * 36 + 16 + lx] = a10[j] + a11[j];
        }
        __syncthreads();   // sync A: pre0 + pre1 complete

        // ---- gates: 1 state per thread; then tail x-prefetch ----
        {
            int base = grow_ * 36;
            float pf = pre0[base + gdd]      + pre1[base + gdd]      + bF;
            float pi = pre0[base + 8 + gdd]  + pre1[base + 8 + gdd]  + bI;
            float po = pre0[base + 16 + gdd] + pre1[base + 16 + gdd] + bO;
            float pc = pre0[base + 24 + gdd] + pre1[base + 24 + gdd] + bC;
            float f  = 1.f / (1.f + __expf(-pf));
            float ig = 1.f / (1.f + __expf(-pi));
            float o  = 1.f / (1.f + __expf(-po));
            float e2 = __expf(2.f * pc);
            float cc = (e2 - 1.f) / (e2 + 1.f);
            float cn = f * cst + ig * cc;
            cst = cn;
            float e2c = __expf(2.f * cn);
            float th  = (e2c - 1.f) / (e2c + 1.f);
            float h   = o * th;
            if (t < SEQ - 1) {
                // coalesced publish: thread tid -> hnext[cb*512 + tid]
                ushort* hw = hbuf + (size_t)(((t + 1) & 1) * 2 + rg) * (128 * 512) + cb * 512 + tid;
                __hip_atomic_store(hw, f2bf(h), __ATOMIC_RELAXED, __HIP_MEMORY_SCOPE_AGENT);
            } else {
                int gr = rg * 64 + grow_;
                out[gr * 2048 + gd] = h;
                out[gr * 2048 + 1024 + gd] = cn;
            }
        }

        if (t < SEQ - 1) {
            // issue x(t+1) loads NOW — they fly during the publish-ack +
            // barrier + flag window and are drained by syncB's vmcnt(0)
            {
                const ushort* xr = emb + (size_t)fidxn * DIMS + kb;
                #pragma unroll
                for (int ks = 0; ks < 16; ks++) {
                    const ushort* xp = xr + ks * 32 + kg;
                    asm volatile("global_load_dwordx4 %0, %1, off"
                                 : "=v"(xv[ks]) : "v"(xp) : "memory");
                }
                if (t + 2 < SEQ) fidxn = feats[brow * SEQ + t + 2];
            }
            asm volatile("s_waitcnt vmcnt(0)" ::: "memory");  // publish acked (+ xv resident)
            __syncthreads();                                   // sync B
            if (tid == 0) {
                __hip_atomic_store(myflags + cb, t + 1, __ATOMIC_RELAXED, __HIP_MEMORY_SCOPE_AGENT);
            }
        }
    }
}

extern "C" void kernel_launch(void* const* d_in, const int* in_sizes, int n_in,
                              void* d_out, int out_size, void* d_ws, size_t ws_size,
                              hipStream_t stream) {
    const int*   feats = (const int*)d_in[0];
    const float* emb_f = (const float*)d_in[1];
    const float* Wf = (const float*)d_in[2];
    const float* Uf = (const float*)d_in[3];
    const float* bf_ = (const float*)d_in[4];
    const float* Wi = (const float*)d_in[5];
    const float* Ui = (const float*)d_in[6];
    const float* bi_ = (const float*)d_in[7];
    const float* Wo = (const float*)d_in[8];
    const float* Uo = (const float*)d_in[9];
    const float* bo_ = (const float*)d_in[10];
    const float* Wc = (const float*)d_in[11];
    const float* Uc = (const float*)d_in[12];
    const float* bc_ = (const float*)d_in[13];

    char* ws = (char*)d_ws;
    ushort* emb_bf = (ushort*)ws;                          // 65,536,000 B
    ushort* hbuf   = (ushort*)(ws + 65536000);             // 2x2x128x64x8 bf16 = 524,288 B
    int*    flags  = (int*)(ws + 65536000 + 524288);       // 256 flags

    hipMemsetAsync(flags, 0, 1024, stream);
    conv_emb_kernel<<<1024, 256, 0, stream>>>(emb_f, emb_bf, VOCAB * DIMS);
    lstm_kernel<<<GRID, 512, 0, stream>>>(feats, emb_bf,
                                          Wf, Uf, bf_, Wi, Ui, bi_,
                                          Wo, Uo, bo_, Wc, Uc, bc_,
                                          hbuf, (float*)d_out, flags);
}

// Round 18
// 3510.294 us; speedup vs baseline: 3.1944x; 1.1502x over previous
//
#include <hip/hip_runtime.h>
#include <hip/hip_bf16.h>

#define DIMS 1024
#define SEQ 512
#define BATCH 128
#define VOCAB 32000
#define GRID 256

typedef __attribute__((ext_vector_type(8))) short short8;
typedef __attribute__((ext_vector_type(16))) float f32x16;

__device__ __forceinline__ ushort f2bf(float x) {
    union { float f; unsigned u; } v; v.f = x;
    unsigned u = v.u;
    return (ushort)((u + 0x7FFFu + ((u >> 16) & 1u)) >> 16);
}

__global__ void conv_emb_kernel(const float* __restrict__ in, ushort* __restrict__ out, int n) {
    int idx = blockIdx.x * blockDim.x + threadIdx.x;
    int stride = gridDim.x * blockDim.x;
    for (int i = idx * 4; i < n; i += stride * 4) {
        float4 v = *(const float4*)(in + i);
        ushort4 o;
        o.x = f2bf(v.x); o.y = f2bf(v.y); o.z = f2bf(v.z); o.w = f2bf(v.w);
        *(ushort4*)(out + i) = o;
    }
}

// Persistent LSTM, fence-free flag sync, 32x32x16 MFMA core.
// 8 waves = 2 row-halves (one 32x32 output tile each) x 4 K-quarters
// (256k x-leg + 256k h-leg per wave). Each MFMA consumes a 1KB B-fragment
// read ONCE per 32k FLop (vs 16k before): LDS B-traffic halves
// (512KB -> 256KB per CU-step; R14's profile showed LDS phase-storms as the
// largest unattacked term; bank-conflict counter = count-proportional).
// 4 K-partials reduce via two-phase LDS: kq{0,1} write pre0/pre1, barrier,
// kq{2,3} read-add-write (exclusive addrs), barrier, gates as before.
// Load schedule per wave = R14's proven one: x ks0-7 -> poll -> asm-batch
// 16 h-loads -> x ks8-15 -> vmcnt(0) -> h-MFMA from registers.
__launch_bounds__(512, 2)
__global__ void lstm_kernel(const int* __restrict__ feats,
                            const ushort* __restrict__ emb,
                            const float* __restrict__ Wf, const float* __restrict__ Uf, const float* __restrict__ bfp,
                            const float* __restrict__ Wi, const float* __restrict__ Ui, const float* __restrict__ bip,
                            const float* __restrict__ Wo, const float* __restrict__ Uo, const float* __restrict__ bop,
                            const float* __restrict__ Wc, const float* __restrict__ Uc, const float* __restrict__ bcp,
                            ushort* __restrict__ hbuf, float* __restrict__ out, int* __restrict__ flags) {
    __shared__ ushort Bl[32 * 2048];        // 131072 B: B-slice, XOR-swizzled
    __shared__ float pre0[64 * 36];         // partial preacts, kq{0,2}
    __shared__ float pre1[64 * 36];         // partial preacts, kq{1,3}

    const int tid = threadIdx.x;
    const int bid = blockIdx.x;
    const int rg = bid >> 7;      // row group: rows rg*64 .. rg*64+63
    const int cb = bid & 127;     // d-chunk: d = cb*8 .. cb*8+7

    // ---- one-time: load B slice (f32 -> bf16) into LDS ----
    for (int idx = tid; idx < 32 * 2048; idx += 512) {
        int cl2 = idx & 31;
        int k  = idx >> 5;
        int g  = cl2 >> 3, dd0 = cl2 & 7;
        int dw = cb * 8 + dd0;
        const float* Wg = (g == 0) ? Wf : (g == 1) ? Wi : (g == 2) ? Wo : Wc;
        const float* Ug = (g == 0) ? Uf : (g == 1) ? Ui : (g == 2) ? Uo : Uc;
        float v = (k < 1024) ? Wg[k * 1024 + dw] : Ug[(k - 1024) * 1024 + dw];
        int boff = ((cl2 << 12) | (k << 1)) ^ ((cl2 & 7) << 4);
        *(ushort*)((char*)Bl + boff) = f2bf(v);
    }

    const int lane = tid & 63;
    const int w  = tid >> 6;                 // wave 0..7
    const int rh = w & 1;                    // row half: 32-row output tile
    const int kq = w >> 1;                   // K-quarter: 256k per leg
    const int cl = lane & 31;                // A row-in-tile / B col
    const int hi = lane >> 5;                // k-subgroup (0/1) within K=16
    const int lrow = rh * 32 + cl;           // local row 0..63
    const int brow = rg * 64 + lrow;         // global batch row

    const int bbase = (cl << 12) ^ ((cl & 7) << 4);   // B byte base; ^ (k<<1) per read
    const int kxb = kq * 256;                // x k-base for this wave

    float* myPre = (kq & 1) ? pre1 : pre0;   // target partial buffer
    // gate-phase mapping: 1 state per thread: row = tid>>3, dd = tid&7
    const int grow_ = tid >> 3;
    const int gdd   = tid & 7;
    const int gd    = cb * 8 + gdd;
    const float bF = bfp[gd], bI = bip[gd], bO = bop[gd], bC = bcp[gd];

    float cst = 0.f;
    int* myflags = flags + rg * 128;
    int fidx = feats[brow * SEQ];

    __syncthreads();   // Bl ready

    for (int t = 0; t < SEQ; t++) {
        f32x16 ac0 = {0.f}, ac1 = {0.f};
        #pragma unroll
        for (int i = 0; i < 16; i++) { ac0[i] = 0.f; ac1[i] = 0.f; }

        const ushort* xrow = emb + (size_t)fidx * DIMS;
        fidx = (t + 1 < SEQ) ? feats[brow * SEQ + t + 1] : 0;

        // ---- x-leg ks 0..7 (plain loads, compiler-pipelined; covers flag hop) ----
        #pragma unroll
        for (int ks = 0; ks < 8; ks++) {
            int k = kxb + ks * 16 + hi * 8;
            short8 a = *(const short8*)(xrow + k);
            short8 b = *(const short8*)((const char*)Bl + (bbase ^ (k << 1)));
            if (ks & 1) ac1 = __builtin_amdgcn_mfma_f32_32x32x16_bf16(a, b, ac1, 0, 0, 0);
            else        ac0 = __builtin_amdgcn_mfma_f32_32x32x16_bf16(a, b, ac0, 0, 0, 0);
        }

        // ---- poll my K-quarter's 32 producers + asm-batch 16 h-loads ----
        short8 hv[16];
        if (t > 0) {
            long guard = 0;
            for (;;) {
                int f0 = __hip_atomic_load(myflags + kq * 32 + cl, __ATOMIC_RELAXED, __HIP_MEMORY_SCOPE_AGENT);
                if (__all(f0 >= t)) break;
                __builtin_amdgcn_s_sleep(1);
                if (++guard > 100000000L) break;  // deadlock safety valve
            }
            const ushort* hbase = hbuf + (size_t)((t & 1) * 2 + rg) * (128 * 512);
            #pragma unroll
            for (int ks = 0; ks < 16; ks++) {
                int chunk = kq * 32 + ks * 2 + hi;
                const ushort* hp = hbase + (chunk << 9) + lrow * 8;
                asm volatile("global_load_dwordx4 %0, %1, off sc0 sc1"
                             : "=v"(hv[ks]) : "v"(hp) : "memory");
            }
        }

        // ---- x-leg ks 8..15 (hides h-load flight) ----
        #pragma unroll
        for (int ks = 8; ks < 16; ks++) {
            int k = kxb + ks * 16 + hi * 8;
            short8 a = *(const short8*)(xrow + k);
            short8 b = *(const short8*)((const char*)Bl + (bbase ^ (k << 1)));
            if (ks & 1) ac1 = __builtin_amdgcn_mfma_f32_32x32x16_bf16(a, b, ac1, 0, 0, 0);
            else        ac0 = __builtin_amdgcn_mfma_f32_32x32x16_bf16(a, b, ac0, 0, 0, 0);
        }

        // ---- h-leg: wait once, then registers + LDS only ----
        if (t > 0) {
            asm volatile("s_waitcnt vmcnt(0)" ::: "memory");
            __builtin_amdgcn_sched_barrier(0);   // rule #18
            #pragma unroll
            for (int ks = 0; ks < 16; ks++) {
                int k = 1024 + kxb + ks * 16 + hi * 8;
                short8 b = *(const short8*)((const char*)Bl + (bbase ^ (k << 1)));
                if (ks & 1) ac1 = __builtin_amdgcn_mfma_f32_32x32x16_bf16(hv[ks], b, ac1, 0, 0, 0);
                else        ac0 = __builtin_amdgcn_mfma_f32_32x32x16_bf16(hv[ks], b, ac0, 0, 0, 0);
            }
        }

        // ---- two-phase partial reduction in LDS ----
        // C/D map (m74/m101): col = lane&31, row = (reg&3) + 8*(reg>>2) + 4*(lane>>5)
        if (kq < 2) {
            #pragma unroll
            for (int r = 0; r < 16; r++) {
                int row = (r & 3) + 8 * (r >> 2) + 4 * hi + rh * 32;
                myPre[row * 36 + cl] = ac0[r] + ac1[r];
            }
        }
        __syncthreads();   // phase A partials in place
        if (kq >= 2) {
            #pragma unroll
            for (int r = 0; r < 16; r++) {
                int row = (r & 3) + 8 * (r >> 2) + 4 * hi + rh * 32;
                myPre[row * 36 + cl] += ac0[r] + ac1[r];
            }
        }
        __syncthreads();   // sync A: pre0 + pre1 complete

        // ---- gates: 1 state per thread ----
        {
            int base = grow_ * 36;
            float pf = pre0[base + gdd]      + pre1[base + gdd]      + bF;
            float pi = pre0[base + 8 + gdd]  + pre1[base + 8 + gdd]  + bI;
            float po = pre0[base + 16 + gdd] + pre1[base + 16 + gdd] + bO;
            float pc = pre0[base + 24 + gdd] + pre1[base + 24 + gdd] + bC;
            float f  = 1.f / (1.f + __expf(-pf));
            float ig = 1.f / (1.f + __expf(-pi));
            float o  = 1.f / (1.f + __expf(-po));
            float e2 = __expf(2.f * pc);
            float cc = (e2 - 1.f) / (e2 + 1.f);
            float cn = f * cst + ig * cc;
            cst = cn;
            float e2c = __expf(2.f * cn);
            float th  = (e2c - 1.f) / (e2c + 1.f);
            float h   = o * th;
            if (t < SEQ - 1) {
                // coalesced publish: thread tid -> hnext[cb*512 + tid]
                ushort* hw = hbuf + (size_t)(((t + 1) & 1) * 2 + rg) * (128 * 512) + cb * 512 + tid;
                __hip_atomic_store(hw, f2bf(h), __ATOMIC_RELAXED, __HIP_MEMORY_SCOPE_AGENT);
            } else {
                int gr = rg * 64 + grow_;
                out[gr * 2048 + gd] = h;
                out[gr * 2048 + 1024 + gd] = cn;
            }
        }

        if (t < SEQ - 1) {
            asm volatile("s_waitcnt vmcnt(0)" ::: "memory");  // h stores acked at coherence point
            __syncthreads();                                   // sync B: publishes done; pre[] reusable
            if (tid == 0) {
                __hip_atomic_store(myflags + cb, t + 1, __ATOMIC_RELAXED, __HIP_MEMORY_SCOPE_AGENT);
            }
        }
    }
}

extern "C" void kernel_launch(void* const* d_in, const int* in_sizes, int n_in,
                              void* d_out, int out_size, void* d_ws, size_t ws_size,
                              hipStream_t stream) {
    const int*   feats = (const int*)d_in[0];
    const float* emb_f = (const float*)d_in[1];
    const float* Wf = (const float*)d_in[2];
    const float* Uf = (const float*)d_in[3];
    const float* bf_ = (const float*)d_in[4];
    const float* Wi = (const float*)d_in[5];
    const float* Ui = (const float*)d_in[6];
    const float* bi_ = (const float*)d_in[7];
    const float* Wo = (const float*)d_in[8];
    const float* Uo = (const float*)d_in[9];
    const float* bo_ = (const float*)d_in[10];
    const float* Wc = (const float*)d_in[11];
    const float* Uc = (const float*)d_in[12];
    const float* bc_ = (const float*)d_in[13];

    char* ws = (char*)d_ws;
    ushort* emb_bf = (ushort*)ws;                          // 65,536,000 B
    ushort* hbuf   = (ushort*)(ws + 65536000);             // 2x2x128x64x8 bf16 = 524,288 B
    int*    flags  = (int*)(ws + 65536000 + 524288);       // 256 flags

    hipMemsetAsync(flags, 0, 1024, stream);
    conv_emb_kernel<<<1024, 256, 0, stream>>>(emb_f, emb_bf, VOCAB * DIMS);
    lstm_kernel<<<GRID, 512, 0, stream>>>(feats, emb_bf,
                                          Wf, Uf, bf_, Wi, Ui, bi_,
                                          Wo, Uo, bo_, Wc, Uc, bc_,
                                          hbuf, (float*)d_out, flags);
}